// Round 11
// baseline (439.519 us; speedup 1.0000x reference)
//
#include <hip/hip_runtime.h>
#include <math.h>

#define NPTS 4096
#define NB 8
#define NTOT (2*NB*NPTS)    // 65536 points
#define EPSF 1e-12f
#define NBKT 256            // buckets per (set,b)
#define NSID 16             // 2 sets x 8 batches

static __device__ __forceinline__ void project_pt(const float* __restrict__ p3,
                                                  const float* __restrict__ Pb,
                                                  float& ix, float& iy){
    float x = p3[0], y = p3[1], z = p3[2];
    float px = fmaf(Pb[0],x, fmaf(Pb[1],y, fmaf(Pb[2],z,  Pb[3])));
    float py = fmaf(Pb[4],x, fmaf(Pb[5],y, fmaf(Pb[6],z,  Pb[7])));
    float pz = fmaf(Pb[8],x, fmaf(Pb[9],y, fmaf(Pb[10],z, Pb[11])));
    ix = px / pz;
    iy = py / pz;
}

// K1: project all points. proj[i] = (ix, iy). set0=gt [0,32768), set1=pred.
__global__ __launch_bounds__(256) void project_all(
        const float* __restrict__ pred, const float* __restrict__ gt,
        const float* __restrict__ P, float2* __restrict__ proj){
    int i = blockIdx.x * 256 + threadIdx.x;
    int set = i >> 15;
    int b   = (i >> 12) & 7;
    const float* src = set ? pred : gt;
    const float* p3  = src + (size_t)(i & 32767) * 3;
    const float* Pb  = P + b * 12;
    float ix, iy; project_pt(p3, Pb, ix, iy);
    proj[i] = make_float2(ix, iy);
}

// K2: per (set,b) slice of 4096 points: x-stats -> 256 equal-width buckets
// (range mean +/- 2.5 sigma, clamped), count, prefix, scatter into binned[].
// Bucket-internal order is atomic-nondeterministic but min is exact ->
// final result deterministic.
__global__ __launch_bounds__(1024) void build_buckets(
        const float2* __restrict__ proj, float2* __restrict__ binned,
        int* __restrict__ off, float2* __restrict__ hdr){
    __shared__ float red[1024];
    __shared__ float stats[2];
    __shared__ int counts[NBKT];
    __shared__ int offs[NBKT];
    __shared__ int cursor[NBKT];
    __shared__ unsigned char pk[NPTS];
    int sid = blockIdx.x;            // set*8 + b
    int t = threadIdx.x;
    int sbase = sid * NPTS;

    float2 c4[4];
    float sx = 0.f, sxx = 0.f;
    #pragma unroll
    for (int k = 0; k < 4; ++k){
        c4[k] = proj[sbase + t + k*1024];
        sx += c4[k].x;
        sxx = fmaf(c4[k].x, c4[k].x, sxx);
    }
    red[t] = sx; __syncthreads();
    for (int o = 512; o > 0; o >>= 1){ if (t < o) red[t] += red[t+o]; __syncthreads(); }
    if (t == 0) stats[0] = red[0];
    __syncthreads();
    red[t] = sxx; __syncthreads();
    for (int o = 512; o > 0; o >>= 1){ if (t < o) red[t] += red[t+o]; __syncthreads(); }
    if (t == 0) stats[1] = red[0];
    if (t < NBKT) counts[t] = 0;
    __syncthreads();

    float mean = stats[0] * (1.0f/NPTS);
    float var  = fmaxf(stats[1] * (1.0f/NPTS) - mean*mean, 0.0f);
    float sig  = sqrtf(var);
    float lo   = mean - 2.5f*sig;
    float span = 5.0f*sig;
    float sc   = (span > 1e-20f) ? ((float)NBKT / span) : 0.0f;

    #pragma unroll
    for (int k = 0; k < 4; ++k){
        int idx = t + k*1024;
        int bk = (int)floorf((c4[k].x - lo) * sc);
        bk = bk < 0 ? 0 : (bk > NBKT-1 ? NBKT-1 : bk);
        pk[idx] = (unsigned char)bk;
        atomicAdd(&counts[bk], 1);
    }
    __syncthreads();

    if (t < NBKT) offs[t] = counts[t];
    __syncthreads();
    for (int s = 1; s < NBKT; s <<= 1){
        int v = 0;
        if (t < NBKT && t >= s) v = offs[t-s];
        __syncthreads();
        if (t < NBKT) offs[t] += v;            // inclusive prefix
        __syncthreads();
    }
    if (t < NBKT){
        cursor[t] = offs[t] - counts[t];       // exclusive start
        off[sid*(NBKT+1) + t + 1] = offs[t];
    }
    if (t == 0){
        off[sid*(NBKT+1)] = 0;
        hdr[sid] = make_float2(lo, sc);
    }
    __syncthreads();

    #pragma unroll
    for (int k = 0; k < 4; ++k){
        int idx = t + k*1024;
        int bk = pk[idx];
        int slot = atomicAdd(&cursor[bk], 1);
        binned[sbase + slot] = c4[k];
    }
}

// K3: per query expanding-bucket NN search (exact), sqrt, block tree-sum.
// 256 blocks = dir(1) x b(3) x qgroup(4 bits); 256 threads = 1 query each.
__global__ __launch_bounds__(256) void nn_search(
        const float2* __restrict__ proj, const float2* __restrict__ binned,
        const int* __restrict__ off, const float2* __restrict__ hdr,
        float* __restrict__ partials){
    __shared__ float sm[256];
    int bid = blockIdx.x;
    int t   = threadIdx.x;
    int qg  = bid & 15;
    int b   = (bid >> 4) & 7;
    int dir = (bid >> 7) & 1;

    float2 a = proj[dir*32768 + b*NPTS + qg*256 + t];
    int sid = (1 - dir)*8 + b;
    const float2* __restrict__ cb = binned + (size_t)sid * NPTS;
    const int*    __restrict__ op = off + sid*(NBKT+1);
    float lo = hdr[sid].x, sc = hdr[sid].y;
    float w  = (sc > 0.0f) ? (1.0f / sc) : 3.4e38f;

    int q0 = (int)floorf((a.x - lo) * sc);
    q0 = q0 < 0 ? 0 : (q0 > NBKT-1 ? NBKT-1 : q0);

    float dmin = 1e30f;
    {
        int e = op[q0+1];
        for (int i = op[q0]; i < e; ++i){
            float2 c = cb[i];
            float dx = a.x - c.x, dy = a.y - c.y;
            dmin = fminf(dmin, fmaf(dy, dy, dx*dx));
        }
    }
    int L = q0 - 1, R = q0 + 1;
    while (true){
        bool lok = (L >= 0), rok = (R <= NBKT-1);
        if (!lok && !rok) break;
        float dL = lok ? (a.x - (lo + (float)(L+1)*w)) : 3.4e38f;
        float dR = rok ? ((lo + (float)R*w) - a.x)     : 3.4e38f;
        float dL2 = dL*dL, dR2 = dR*dR;
        if (fminf(dL2, dR2) >= dmin) break;
        int k;
        if (dL2 <= dR2){ k = L; --L; } else { k = R; ++R; }
        int e = op[k+1];
        for (int i = op[k]; i < e; ++i){
            float2 c = cb[i];
            float dx = a.x - c.x, dy = a.y - c.y;
            dmin = fminf(dmin, fmaf(dy, dy, dx*dx));
        }
    }

    sm[t] = sqrtf(fmaxf(dmin, EPSF));
    __syncthreads();
    #pragma unroll
    for (int o = 128; o > 0; o >>= 1){
        if (t < o) sm[t] += sm[t + o];
        __syncthreads();
    }
    if (t == 0) partials[bid] = sm[0];
}

// K4: fixed-order tree sum of 256 partials, scale by 1/(B*N).
__global__ __launch_bounds__(256) void reduce_final(
        const float* __restrict__ partials, float* __restrict__ out){
    __shared__ float sm[256];
    int t = threadIdx.x;
    sm[t] = partials[t];
    __syncthreads();
    #pragma unroll
    for (int o = 128; o > 0; o >>= 1){
        if (t < o) sm[t] += sm[t + o];
        __syncthreads();
    }
    if (t == 0) out[0] = sm[0] * (1.0f / 32768.0f);
}

extern "C" void kernel_launch(void* const* d_in, const int* in_sizes, int n_in,
                              void* d_out, int out_size, void* d_ws, size_t ws_size,
                              hipStream_t stream) {
    const float* pred = (const float*)d_in[0];
    const float* gt   = (const float*)d_in[1];
    const float* P    = (const float*)d_in[2];
    float* out = (float*)d_out;

    char* w = (char*)d_ws;
    float2* proj     = (float2*)w;                                  w += (size_t)NTOT*8;   // 512 KB
    float2* binned   = (float2*)w;                                  w += (size_t)NTOT*8;   // 512 KB
    int*    off      = (int*)w;                                     w += (size_t)NSID*(NBKT+1)*4;
    float2* hdr      = (float2*)w;                                  w += (size_t)NSID*8;
    float*  partials = (float*)w;

    project_all  <<<NTOT/256, 256, 0, stream>>>(pred, gt, P, proj);
    build_buckets<<<NSID, 1024, 0, stream>>>(proj, binned, off, hdr);
    nn_search    <<<256, 256, 0, stream>>>(proj, binned, off, hdr, partials);
    reduce_final <<<1, 256, 0, stream>>>(partials, out);
}

// Round 12
// 274.342 us; speedup vs baseline: 1.6021x; 1.6021x over previous
//
#include <hip/hip_runtime.h>
#include <math.h>

#define NPTS 4096
#define NB 8
#define NTOT (2*NB*NPTS)    // 65536 points
#define EPSF 1e-12f
#define NBKT 256            // buckets per (set,b)
#define NSID 16             // 2 sets x 8 batches

static __device__ __forceinline__ void project_pt(const float* __restrict__ p3,
                                                  const float* __restrict__ Pb,
                                                  float& ix, float& iy){
    float x = p3[0], y = p3[1], z = p3[2];
    float px = fmaf(Pb[0],x, fmaf(Pb[1],y, fmaf(Pb[2],z,  Pb[3])));
    float py = fmaf(Pb[4],x, fmaf(Pb[5],y, fmaf(Pb[6],z,  Pb[7])));
    float pz = fmaf(Pb[8],x, fmaf(Pb[9],y, fmaf(Pb[10],z, Pb[11])));
    ix = px / pz;
    iy = py / pz;
}

// K1 (fused project + bucket build), one block per (set,b) slice of 4096 pts:
// project -> x-stats -> 256 equal-width buckets (mean +/- 2.5 sigma, clamped)
// -> count -> prefix -> scatter (x,y) AND original index into binned/bIdx.
// Bucket-internal order is atomic-nondeterministic; consumers are order-
// invariant (exact min + index-scatter), so the final output is deterministic.
__global__ __launch_bounds__(1024) void build_buckets(
        const float* __restrict__ pred, const float* __restrict__ gt,
        const float* __restrict__ P,
        float2* __restrict__ binned, int* __restrict__ bIdx,
        int* __restrict__ off, float2* __restrict__ hdr){
    __shared__ float red[1024];
    __shared__ float stats[2];
    __shared__ int counts[NBKT];
    __shared__ int offs[NBKT];
    __shared__ int cursor[NBKT];
    __shared__ unsigned char pk[NPTS];
    int sid = blockIdx.x;            // set*8 + b
    int t = threadIdx.x;
    int set = sid >> 3, b = sid & 7;
    const float* src = set ? pred : gt;
    const float* Pb  = P + b * 12;
    int sbase = sid * NPTS;

    float2 c4[4];
    float sx = 0.f, sxx = 0.f;
    #pragma unroll
    for (int k = 0; k < 4; ++k){
        int idx = t + k*1024;
        const float* p3 = src + (size_t)(b*NPTS + idx) * 3;
        float ix, iy; project_pt(p3, Pb, ix, iy);
        c4[k] = make_float2(ix, iy);
        sx += ix;
        sxx = fmaf(ix, ix, sxx);
    }
    red[t] = sx; __syncthreads();
    for (int o = 512; o > 0; o >>= 1){ if (t < o) red[t] += red[t+o]; __syncthreads(); }
    if (t == 0) stats[0] = red[0];
    __syncthreads();
    red[t] = sxx; __syncthreads();
    for (int o = 512; o > 0; o >>= 1){ if (t < o) red[t] += red[t+o]; __syncthreads(); }
    if (t == 0) stats[1] = red[0];
    if (t < NBKT) counts[t] = 0;
    __syncthreads();

    float mean = stats[0] * (1.0f/NPTS);
    float var  = fmaxf(stats[1] * (1.0f/NPTS) - mean*mean, 0.0f);
    float sig  = sqrtf(var);
    float lo   = mean - 2.5f*sig;
    float span = 5.0f*sig;
    float sc   = (span > 1e-20f) ? ((float)NBKT / span) : 0.0f;

    #pragma unroll
    for (int k = 0; k < 4; ++k){
        int idx = t + k*1024;
        int bk = (int)floorf((c4[k].x - lo) * sc);
        bk = bk < 0 ? 0 : (bk > NBKT-1 ? NBKT-1 : bk);
        pk[idx] = (unsigned char)bk;
        atomicAdd(&counts[bk], 1);
    }
    __syncthreads();

    if (t < NBKT) offs[t] = counts[t];
    __syncthreads();
    for (int s = 1; s < NBKT; s <<= 1){
        int v = 0;
        if (t < NBKT && t >= s) v = offs[t-s];
        __syncthreads();
        if (t < NBKT) offs[t] += v;            // inclusive prefix
        __syncthreads();
    }
    if (t < NBKT){
        cursor[t] = offs[t] - counts[t];       // exclusive start
        off[sid*(NBKT+1) + t + 1] = offs[t];
    }
    if (t == 0){
        off[sid*(NBKT+1)] = 0;
        hdr[sid] = make_float2(lo, sc);
    }
    __syncthreads();

    #pragma unroll
    for (int k = 0; k < 4; ++k){
        int idx = t + k*1024;
        int bk = pk[idx];
        int slot = atomicAdd(&cursor[bk], 1);
        binned[sbase + slot] = c4[k];
        bIdx[sbase + slot]  = idx;
    }
}

// K2: NN search. Queries consumed in BUCKET-GROUPED order (the binned array
// itself) so each wave's lanes are spatially adjacent -> coherent expansion.
// Candidate slice (32 KB) + offsets staged in LDS. Result scattered to
// dArr[original query index] -> downstream sum order is fixed.
__global__ __launch_bounds__(256) void nn_search(
        const float2* __restrict__ binned, const int* __restrict__ bIdx,
        const int* __restrict__ off, const float2* __restrict__ hdr,
        float* __restrict__ dArr){
    __shared__ float2 cs[NPTS];      // candidate slice
    __shared__ int    so[NBKT+1];
    int bid = blockIdx.x;
    int t   = threadIdx.x;
    int sidq = bid >> 4;             // 16 blocks per query sid
    int set  = sidq >> 3, b = sidq & 7;
    int sidc = (1 - set)*8 + b;

    for (int i = t; i < NPTS; i += 256) cs[i] = binned[(size_t)sidc*NPTS + i];
    for (int i = t; i <= NBKT; i += 256) so[i] = off[sidc*(NBKT+1) + i];

    int qslot = (bid & 15)*256 + t;
    float2 a = binned[(size_t)sidq*NPTS + qslot];
    int    oi = bIdx[(size_t)sidq*NPTS + qslot];
    float lo = hdr[sidc].x, sc = hdr[sidc].y;
    float w  = (sc > 0.0f) ? (1.0f / sc) : 3.4e38f;
    __syncthreads();

    int q0 = (int)floorf((a.x - lo) * sc);
    q0 = q0 < 0 ? 0 : (q0 > NBKT-1 ? NBKT-1 : q0);

    float dmin = 1e30f;
    {
        int e = so[q0+1];
        for (int i = so[q0]; i < e; ++i){
            float2 c = cs[i];
            float dx = a.x - c.x, dy = a.y - c.y;
            dmin = fminf(dmin, fmaf(dy, dy, dx*dx));
        }
    }
    int L = q0 - 1, R = q0 + 1;
    while (true){
        bool lok = (L >= 0), rok = (R <= NBKT-1);
        if (!lok && !rok) break;
        float dL = lok ? (a.x - (lo + (float)(L+1)*w)) : 3.4e38f;
        float dR = rok ? ((lo + (float)R*w) - a.x)     : 3.4e38f;
        float dL2 = dL*dL, dR2 = dR*dR;
        if (fminf(dL2, dR2) >= dmin) break;
        int k;
        if (dL2 <= dR2){ k = L; --L; } else { k = R; ++R; }
        int e = so[k+1];
        for (int i = so[k]; i < e; ++i){
            float2 c = cs[i];
            float dx = a.x - c.x, dy = a.y - c.y;
            dmin = fminf(dmin, fmaf(dy, dy, dx*dx));
        }
    }

    dArr[(size_t)sidq*NPTS + oi] = sqrtf(fmaxf(dmin, EPSF));
}

// K3: fixed-order per-block tree sums over dArr (256 blocks x 256).
__global__ __launch_bounds__(256) void reduce_sum(
        const float* __restrict__ dArr, float* __restrict__ partials){
    __shared__ float sm[256];
    int t = threadIdx.x;
    sm[t] = dArr[blockIdx.x * 256 + t];
    __syncthreads();
    #pragma unroll
    for (int o = 128; o > 0; o >>= 1){
        if (t < o) sm[t] += sm[t + o];
        __syncthreads();
    }
    if (t == 0) partials[blockIdx.x] = sm[0];
}

// K4: fixed-order tree sum of 256 partials, scale by 1/(B*N).
__global__ __launch_bounds__(256) void reduce_final(
        const float* __restrict__ partials, float* __restrict__ out){
    __shared__ float sm[256];
    int t = threadIdx.x;
    sm[t] = partials[t];
    __syncthreads();
    #pragma unroll
    for (int o = 128; o > 0; o >>= 1){
        if (t < o) sm[t] += sm[t + o];
        __syncthreads();
    }
    if (t == 0) out[0] = sm[0] * (1.0f / 32768.0f);
}

extern "C" void kernel_launch(void* const* d_in, const int* in_sizes, int n_in,
                              void* d_out, int out_size, void* d_ws, size_t ws_size,
                              hipStream_t stream) {
    const float* pred = (const float*)d_in[0];
    const float* gt   = (const float*)d_in[1];
    const float* P    = (const float*)d_in[2];
    float* out = (float*)d_out;

    char* w = (char*)d_ws;
    float2* binned   = (float2*)w;   w += (size_t)NTOT*8;              // 512 KB
    int*    bIdx     = (int*)w;      w += (size_t)NTOT*4;              // 256 KB
    float*  dArr     = (float*)w;    w += (size_t)NTOT*4;              // 256 KB
    int*    off      = (int*)w;      w += (size_t)NSID*(NBKT+1)*4;
    float2* hdr      = (float2*)w;   w += 256;
    float*  partials = (float*)w;

    build_buckets<<<NSID, 1024, 0, stream>>>(pred, gt, P, binned, bIdx, off, hdr);
    nn_search    <<<256, 256, 0, stream>>>(binned, bIdx, off, hdr, dArr);
    reduce_sum   <<<256, 256, 0, stream>>>(dArr, partials);
    reduce_final <<<1, 256, 0, stream>>>(partials, out);
}

// Round 13
// 178.321 us; speedup vs baseline: 2.4648x; 1.5385x over previous
//
#include <hip/hip_runtime.h>
#include <math.h>

#define NPTS 4096
#define NB 8
#define NTOT (2*NB*NPTS)    // 65536 points
#define EPSF 1e-12f
#define NBKT 256            // buckets per (set,b)
#define NSID 16             // 2 sets x 8 batches

static __device__ __forceinline__ void project_pt(const float* __restrict__ p3,
                                                  const float* __restrict__ Pb,
                                                  float& ix, float& iy){
    float x = p3[0], y = p3[1], z = p3[2];
    float px = fmaf(Pb[0],x, fmaf(Pb[1],y, fmaf(Pb[2],z,  Pb[3])));
    float py = fmaf(Pb[4],x, fmaf(Pb[5],y, fmaf(Pb[6],z,  Pb[7])));
    float pz = fmaf(Pb[8],x, fmaf(Pb[9],y, fmaf(Pb[10],z, Pb[11])));
    ix = px / pz;
    iy = py / pz;
}

// K1 (fused project + bucket build) — unchanged from R12 (measured ~2 us).
__global__ __launch_bounds__(1024) void build_buckets(
        const float* __restrict__ pred, const float* __restrict__ gt,
        const float* __restrict__ P,
        float2* __restrict__ binned, int* __restrict__ bIdx,
        int* __restrict__ off, float2* __restrict__ hdr){
    __shared__ float red[1024];
    __shared__ float stats[2];
    __shared__ int counts[NBKT];
    __shared__ int offs[NBKT];
    __shared__ int cursor[NBKT];
    __shared__ unsigned char pk[NPTS];
    int sid = blockIdx.x;            // set*8 + b
    int t = threadIdx.x;
    int set = sid >> 3, b = sid & 7;
    const float* src = set ? pred : gt;
    const float* Pb  = P + b * 12;
    int sbase = sid * NPTS;

    float2 c4[4];
    float sx = 0.f, sxx = 0.f;
    #pragma unroll
    for (int k = 0; k < 4; ++k){
        int idx = t + k*1024;
        const float* p3 = src + (size_t)(b*NPTS + idx) * 3;
        float ix, iy; project_pt(p3, Pb, ix, iy);
        c4[k] = make_float2(ix, iy);
        sx += ix;
        sxx = fmaf(ix, ix, sxx);
    }
    red[t] = sx; __syncthreads();
    for (int o = 512; o > 0; o >>= 1){ if (t < o) red[t] += red[t+o]; __syncthreads(); }
    if (t == 0) stats[0] = red[0];
    __syncthreads();
    red[t] = sxx; __syncthreads();
    for (int o = 512; o > 0; o >>= 1){ if (t < o) red[t] += red[t+o]; __syncthreads(); }
    if (t == 0) stats[1] = red[0];
    if (t < NBKT) counts[t] = 0;
    __syncthreads();

    float mean = stats[0] * (1.0f/NPTS);
    float var  = fmaxf(stats[1] * (1.0f/NPTS) - mean*mean, 0.0f);
    float sig  = sqrtf(var);
    float lo   = mean - 2.5f*sig;
    float span = 5.0f*sig;
    float sc   = (span > 1e-20f) ? ((float)NBKT / span) : 0.0f;

    #pragma unroll
    for (int k = 0; k < 4; ++k){
        int idx = t + k*1024;
        int bk = (int)floorf((c4[k].x - lo) * sc);
        bk = bk < 0 ? 0 : (bk > NBKT-1 ? NBKT-1 : bk);
        pk[idx] = (unsigned char)bk;
        atomicAdd(&counts[bk], 1);
    }
    __syncthreads();

    if (t < NBKT) offs[t] = counts[t];
    __syncthreads();
    for (int s = 1; s < NBKT; s <<= 1){
        int v = 0;
        if (t < NBKT && t >= s) v = offs[t-s];
        __syncthreads();
        if (t < NBKT) offs[t] += v;            // inclusive prefix
        __syncthreads();
    }
    if (t < NBKT){
        cursor[t] = offs[t] - counts[t];       // exclusive start
        off[sid*(NBKT+1) + t + 1] = offs[t];
    }
    if (t == 0){
        off[sid*(NBKT+1)] = 0;
        hdr[sid] = make_float2(lo, sc);
    }
    __syncthreads();

    #pragma unroll
    for (int k = 0; k < 4; ++k){
        int idx = t + k*1024;
        int bk = pk[idx];
        int slot = atomicAdd(&cursor[bk], 1);
        binned[sbase + slot] = c4[k];
        bIdx[sbase + slot]  = idx;
    }
}

// K2: WAVE-COOPERATIVE NN search. Lanes of a wave hold x-adjacent queries;
// the scan window [kLo..kHi] and its expansion are wave-uniform (SGPR loop
// bounds, broadcast LDS reads, no divergence). Per-lane exact min; result
// scattered to original index -> deterministic downstream sum.
__global__ __launch_bounds__(256) void nn_search(
        const float2* __restrict__ binned, const int* __restrict__ bIdx,
        const int* __restrict__ off, const float2* __restrict__ hdr,
        float* __restrict__ dArr){
    __shared__ float2 cs[NPTS];      // candidate slice (32 KB)
    __shared__ int    so[NBKT+1];
    int bid = blockIdx.x;
    int t   = threadIdx.x;
    int sidq = bid >> 4;             // 16 blocks per query sid
    int set  = sidq >> 3, b = sidq & 7;
    int sidc = (1 - set)*8 + b;

    for (int i = t; i < NPTS; i += 256) cs[i] = binned[(size_t)sidc*NPTS + i];
    for (int i = t; i <= NBKT; i += 256) so[i] = off[sidc*(NBKT+1) + i];

    int qslot = (bid & 15)*256 + t;
    float2 a = binned[(size_t)sidq*NPTS + qslot];
    int    oi = bIdx[(size_t)sidq*NPTS + qslot];
    float lo = hdr[sidc].x, sc = hdr[sidc].y;
    float w  = (sc > 0.0f) ? (1.0f / sc) : 3.4e38f;
    __syncthreads();

    int q0 = (int)floorf((a.x - lo) * sc);
    q0 = q0 < 0 ? 0 : (q0 > NBKT-1 ? NBKT-1 : q0);

    // wave-uniform window bounds
    int kLo = q0, kHi = q0;
    #pragma unroll
    for (int o = 32; o > 0; o >>= 1){
        kLo = min(kLo, __shfl_xor(kLo, o));
        kHi = max(kHi, __shfl_xor(kHi, o));
    }

    float dm0 = 1e30f, dm1 = 1e30f;
    // initial window: contiguous candidate range, broadcast reads, 2-unrolled
    {
        int s = so[kLo], e = so[kHi+1];
        int i = s;
        for (; i + 1 < e; i += 2){
            float2 c0 = cs[i], c1 = cs[i+1];
            float dx0 = a.x - c0.x, dy0 = a.y - c0.y;
            float dx1 = a.x - c1.x, dy1 = a.y - c1.y;
            dm0 = fminf(dm0, fmaf(dy0, dy0, dx0*dx0));
            dm1 = fminf(dm1, fmaf(dy1, dy1, dx1*dx1));
        }
        if (i < e){
            float2 c = cs[i];
            float dx = a.x - c.x, dy = a.y - c.y;
            dm0 = fminf(dm0, fmaf(dy, dy, dx*dx));
        }
    }

    int L = kLo - 1, R = kHi + 1;
    while (true){
        float dmin = fminf(dm0, dm1) * 1.00001f;   // guard band for edge rounding
        float edgeL = fmaf((float)(L+1), w, lo);
        float edgeR = fmaf((float)R, w, lo);
        float dL = a.x - edgeL;
        float dR = edgeR - a.x;
        bool wantL = (L >= 0) && (dL*dL < dmin);
        bool wantR = (R <= NBKT-1) && (dR*dR < dmin);
        bool anyL = __any(wantL), anyR = __any(wantR);
        if (!anyL && !anyR) break;
        if (anyL){
            int s = so[L], e = so[L+1];
            int i = s;
            for (; i + 1 < e; i += 2){
                float2 c0 = cs[i], c1 = cs[i+1];
                float dx0 = a.x - c0.x, dy0 = a.y - c0.y;
                float dx1 = a.x - c1.x, dy1 = a.y - c1.y;
                dm0 = fminf(dm0, fmaf(dy0, dy0, dx0*dx0));
                dm1 = fminf(dm1, fmaf(dy1, dy1, dx1*dx1));
            }
            if (i < e){
                float2 c = cs[i];
                float dx = a.x - c.x, dy = a.y - c.y;
                dm0 = fminf(dm0, fmaf(dy, dy, dx*dx));
            }
            --L;
        }
        if (anyR){
            int s = so[R], e = so[R+1];
            int i = s;
            for (; i + 1 < e; i += 2){
                float2 c0 = cs[i], c1 = cs[i+1];
                float dx0 = a.x - c0.x, dy0 = a.y - c0.y;
                float dx1 = a.x - c1.x, dy1 = a.y - c1.y;
                dm0 = fminf(dm0, fmaf(dy0, dy0, dx0*dx0));
                dm1 = fminf(dm1, fmaf(dy1, dy1, dx1*dx1));
            }
            if (i < e){
                float2 c = cs[i];
                float dx = a.x - c.x, dy = a.y - c.y;
                dm1 = fminf(dm1, fmaf(dy, dy, dx*dx));
            }
            ++R;
        }
    }

    float dmin = fminf(dm0, dm1);
    dArr[(size_t)sidq*NPTS + oi] = sqrtf(fmaxf(dmin, EPSF));
}

// K3: fixed-order per-block tree sums over dArr (256 blocks x 256).
__global__ __launch_bounds__(256) void reduce_sum(
        const float* __restrict__ dArr, float* __restrict__ partials){
    __shared__ float sm[256];
    int t = threadIdx.x;
    sm[t] = dArr[blockIdx.x * 256 + t];
    __syncthreads();
    #pragma unroll
    for (int o = 128; o > 0; o >>= 1){
        if (t < o) sm[t] += sm[t + o];
        __syncthreads();
    }
    if (t == 0) partials[blockIdx.x] = sm[0];
}

// K4: fixed-order tree sum of 256 partials, scale by 1/(B*N).
__global__ __launch_bounds__(256) void reduce_final(
        const float* __restrict__ partials, float* __restrict__ out){
    __shared__ float sm[256];
    int t = threadIdx.x;
    sm[t] = partials[t];
    __syncthreads();
    #pragma unroll
    for (int o = 128; o > 0; o >>= 1){
        if (t < o) sm[t] += sm[t + o];
        __syncthreads();
    }
    if (t == 0) out[0] = sm[0] * (1.0f / 32768.0f);
}

extern "C" void kernel_launch(void* const* d_in, const int* in_sizes, int n_in,
                              void* d_out, int out_size, void* d_ws, size_t ws_size,
                              hipStream_t stream) {
    const float* pred = (const float*)d_in[0];
    const float* gt   = (const float*)d_in[1];
    const float* P    = (const float*)d_in[2];
    float* out = (float*)d_out;

    char* w = (char*)d_ws;
    float2* binned   = (float2*)w;   w += (size_t)NTOT*8;              // 512 KB
    int*    bIdx     = (int*)w;      w += (size_t)NTOT*4;              // 256 KB
    float*  dArr     = (float*)w;    w += (size_t)NTOT*4;              // 256 KB
    int*    off      = (int*)w;      w += (size_t)NSID*(NBKT+1)*4;
    float2* hdr      = (float2*)w;   w += 256;
    float*  partials = (float*)w;

    build_buckets<<<NSID, 1024, 0, stream>>>(pred, gt, P, binned, bIdx, off, hdr);
    nn_search    <<<256, 256, 0, stream>>>(binned, bIdx, off, hdr, dArr);
    reduce_sum   <<<256, 256, 0, stream>>>(dArr, partials);
    reduce_final <<<1, 256, 0, stream>>>(partials, out);
}